// Round 14
// baseline (199.429 us; speedup 1.0000x reference)
//
#include <hip/hip_runtime.h>
#include <hip/hip_fp16.h>

// GCN: 3x (GEMM(+BN fold from gstats) -> CSR aggregate(+slot-replicated atomic
// BN partials)), then fused pool+head (one block per graph).
// Sizes fixed: N=65536 nodes, E=1048576 edges, F=H=64, 64 graphs, 16 classes.
//
// r8 (188us): 4096-edge bin, scalar-LDS gemm, LDS-staged agg windows.
// r9 ticket+fence = L2 storm. r10/r11: single-copy atomic stats = same-line
// tail. r12 (192us): 16-slot replicated gstats fixed the tail, 12 dispatches.
// r13/r14: launch-gap attack (~7us/dispatch by arithmetic): scanB folded into
// place (per-block redundant 512-scan); pool+head fused one-block-per-graph
// via binary search on sorted batch. 10 dispatches. (r13 = compile typo.)

#define NBKT 512      // bucket = dst >> 7 (128 nodes per bucket)
#define CAP  4096     // slots per bucket (avg fill 2048)
#define BSTRIDE 16    // padded: one counter per 64B line
#define NSLOT 16      // gstats replication factor
#define GSL   2048    // floats per gstats slot (128 features x 16-stride)

__device__ inline unsigned pack2h(float a, float b) {
    __half ha = __float2half_rn(a), hb = __float2half_rn(b);
    unsigned short ua = *(unsigned short*)&ha, ub = *(unsigned short*)&hb;
    return (unsigned)ua | ((unsigned)ub << 16);
}

__device__ inline void acc8(float* a, uint4 u) {
    __half2* hp = (__half2*)&u;
#pragma unroll
    for (int i = 0; i < 4; ++i) {
        float2 f = __half22float2(hp[i]);
        a[2 * i] += f.x;
        a[2 * i + 1] += f.y;
    }
}

// init bcur + zero gstats (3 layers x 16 slots). 128 blocks.
__global__ void k_binit(int* __restrict__ bcur, float* __restrict__ gstats) {
    int idx = blockIdx.x * 256 + threadIdx.x;   // 0..32767
    if (idx < NBKT) bcur[idx * BSTRIDE] = idx * CAP;
    for (int i = idx; i < 3 * NSLOT * GSL; i += 32768) gstats[i] = 0.0f;
}

// partition edges into NBKT dst-buckets; entries packed (src<<7)|(dst&127)
// 4096 edges/block (r8-proven: 256 blocks, 28KB LDS)
__global__ void k_bin(const int* __restrict__ ei, int E, int* __restrict__ bcur,
                      int* __restrict__ buck) {
    __shared__ int sd[4096];
    __shared__ unsigned short bk[4096];
    __shared__ int cnt[NBKT], off[NBKT];
    int t = threadIdx.x;
    int base = blockIdx.x * 4096;
    for (int i = t; i < NBKT; i += 256) cnt[i] = 0;
    __syncthreads();
#pragma unroll
    for (int k = 0; k < 16; ++k) {
        int i = k * 256 + t;
        int e = base + i;
        int s = ei[e], d = ei[E + e];
        sd[i] = (s << 7) | (d & 127);
        int b = d >> 7;
        bk[i] = (unsigned short)b;
        atomicAdd(&cnt[b], 1);
    }
    __syncthreads();
    for (int b = t; b < NBKT; b += 256) {
        int c = cnt[b];
        off[b] = c ? atomicAdd(&bcur[b * BSTRIDE], c) : 0;
    }
    __syncthreads();
#pragma unroll
    for (int k = 0; k < 16; ++k) {
        int i = k * 256 + t;
        int b = bk[i];
        int p = atomicAdd(&off[b], 1);
        buck[p] = sd[i];
    }
}

// per bucket: redundant in-block scan of all 512 bucket counts -> base;
// count node degrees in LDS, local 128-scan -> rowptr/dinv, scatter csr.
__global__ __launch_bounds__(512) void k_place(
        const int* __restrict__ bcur, const int* __restrict__ buck,
        int* __restrict__ rowptr, float* __restrict__ dinv, int* __restrict__ csr,
        int N, int E) {
    __shared__ int s[NBKT];
    __shared__ int dc[128], sc[128], cur[128];
    __shared__ int sbase;
    int b = blockIdx.x, t = threadIdx.x;   // 512 threads
    // bucket counts -> inclusive scan (Hillis-Steele over 512)
    s[t] = bcur[t * BSTRIDE] - t * CAP;
    if (t < 128) dc[t] = 0;
    __syncthreads();
    for (int o = 1; o < NBKT; o <<= 1) {
        int x = (t >= o) ? s[t - o] : 0;
        __syncthreads();
        s[t] += x;
        __syncthreads();
    }
    if (t == 0) {
        sbase = (b == 0) ? 0 : s[b - 1];   // exclusive prefix at this bucket
        if (b == NBKT - 1) rowptr[N] = E;
    }
    __syncthreads();
    int beg = b * CAP, end = bcur[b * BSTRIDE];
    for (int i = beg + t; i < end; i += 512) atomicAdd(&dc[buck[i] & 127], 1);
    __syncthreads();
    int v = (t < 128) ? dc[t] : 0;
    if (t < 128) sc[t] = v;
    __syncthreads();
    for (int o = 1; o < 128; o <<= 1) {
        int x = 0;
        if (t < 128 && t >= o) x = sc[t - o];
        __syncthreads();
        if (t < 128) sc[t] += x;
        __syncthreads();
    }
    if (t < 128) {
        int r = sbase + sc[t] - v;   // exclusive
        rowptr[b * 128 + t] = r;
        cur[t] = r;
        dinv[b * 128 + t] = rsqrtf((float)(v + 1));  // +1 self loop
    }
    __syncthreads();
    for (int i = beg + t; i < end; i += 512) {
        int e = buck[i];
        int p = atomicAdd(&cur[e & 127], 1);
        csr[p] = e >> 7;
    }
}

// y[n][j] = fp16( dinv[n] * ( sum_f hnorm[n][f]*W[f][j] + brow[j] ) )
// HS: derive mean/rstd of the PREVIOUS layer from 16-slot gstats; fold into Ws.
// r8-proven body: block 256 threads, 64 rows/block; thread = 4x4 tile.
template <int HIN, int HS>
__global__ void k_gemm(const void* __restrict__ hv, const float* __restrict__ W,
                       const float* __restrict__ gstats, float invN,
                       const float* __restrict__ dinv, __half* __restrict__ y) {
    __shared__ float Ws[4096];        // [f][c] 64x64, scaled by rstd[f]
    __shared__ float hs[64 * 65];     // [row][f], stride 65
    __shared__ float sm[64], sr[64], bs[64];
    int t = threadIdx.x;
    int rowBase = blockIdx.x * 64;
    if (t < 64) {
        if (HS) {
            float S = 0.0f, Q = 0.0f;
#pragma unroll
            for (int c = 0; c < NSLOT; ++c) {
                S += gstats[c * GSL + t * 16];
                Q += gstats[c * GSL + (64 + t) * 16];
            }
            float m = S * invN;
            float var = Q * invN - m * m;
            sm[t] = m;
            sr[t] = rsqrtf(var + 1e-5f);
        } else {
            sm[t] = 0.0f;
            sr[t] = 1.0f;
        }
    }
    __syncthreads();
#pragma unroll
    for (int k = 0; k < 4; ++k) {
        int i = t + k * 256;              // float4 index; row f = i>>4
        float4 wv = ((const float4*)W)[i];
        float s = sr[i >> 4];
        wv.x *= s; wv.y *= s; wv.z *= s; wv.w *= s;
        ((float4*)Ws)[i] = wv;
    }
    if (HIN) {
        const uint4* src = (const uint4*)((const __half*)hv + (size_t)rowBase * 64);
#pragma unroll
        for (int k = 0; k < 2; ++k) {
            int i = t + k * 256;          // 0..511 uint4s; each = 8 halves
            int row = i >> 3, c8 = i & 7;
            uint4 u = src[i];
            const __half2* hp = (const __half2*)&u;
            float* dst = &hs[row * 65 + c8 * 8];
#pragma unroll
            for (int j = 0; j < 4; ++j) {
                dst[2 * j + 0] = __low2float(hp[j]);
                dst[2 * j + 1] = __high2float(hp[j]);
            }
        }
    } else {
        const float4* src = (const float4*)((const float*)hv + (size_t)rowBase * 64);
#pragma unroll
        for (int k = 0; k < 4; ++k) {
            int i = t + k * 256;
            int row = i >> 4, c4 = i & 15;
            float4 v = src[i];
            float* dst = &hs[row * 65 + c4 * 4];
            dst[0] = v.x; dst[1] = v.y; dst[2] = v.z; dst[3] = v.w;
        }
    }
    __syncthreads();
    if (t < 64) {
        float acc = 0.0f;
        for (int f = 0; f < 64; ++f) acc += sm[f] * Ws[f * 64 + t];
        bs[t] = -acc;
    }
    __syncthreads();
    int rg = t >> 4;   // 0..15
    int cg = t & 15;   // 0..15
    float4 a0, a1, a2, a3;
    {
        float bx = bs[cg * 4 + 0], by = bs[cg * 4 + 1];
        float bz = bs[cg * 4 + 2], bw = bs[cg * 4 + 3];
        a0 = {bx, by, bz, bw}; a1 = a0; a2 = a0; a3 = a0;
    }
    const float* h0 = &hs[(rg * 4 + 0) * 65];
    const float* h1 = &hs[(rg * 4 + 1) * 65];
    const float* h2 = &hs[(rg * 4 + 2) * 65];
    const float* h3 = &hs[(rg * 4 + 3) * 65];
#pragma unroll 4
    for (int f = 0; f < 64; ++f) {
        float4 wv = ((float4*)Ws)[f * 16 + cg];
        float v0 = h0[f], v1 = h1[f], v2 = h2[f], v3 = h3[f];
        a0.x += v0 * wv.x; a0.y += v0 * wv.y; a0.z += v0 * wv.z; a0.w += v0 * wv.w;
        a1.x += v1 * wv.x; a1.y += v1 * wv.y; a1.z += v1 * wv.z; a1.w += v1 * wv.w;
        a2.x += v2 * wv.x; a2.y += v2 * wv.y; a2.z += v2 * wv.z; a2.w += v2 * wv.w;
        a3.x += v3 * wv.x; a3.y += v3 * wv.y; a3.z += v3 * wv.z; a3.w += v3 * wv.w;
    }
    float d0 = dinv[rowBase + rg * 4 + 0];
    float d1 = dinv[rowBase + rg * 4 + 1];
    float d2 = dinv[rowBase + rg * 4 + 2];
    float d3 = dinv[rowBase + rg * 4 + 3];
    uint2* y2 = (uint2*)y;
    size_t ob = (size_t)(rowBase + rg * 4) * 16 + cg;
    y2[ob + 0]  = {pack2h(a0.x * d0, a0.y * d0), pack2h(a0.z * d0, a0.w * d0)};
    y2[ob + 16] = {pack2h(a1.x * d1, a1.y * d1), pack2h(a1.z * d1, a1.w * d1)};
    y2[ob + 32] = {pack2h(a2.x * d2, a2.y * d2), pack2h(a2.z * d2, a2.w * d2)};
    y2[ob + 48] = {pack2h(a3.x * d3, a3.y * d3), pack2h(a3.z * d3, a3.w * d3)};
}

// out[n] = relu?( dinv[n]*(y[n] + sum_{src} y[src]) + bias ), stored fp16.
// Block = 64 consecutive nodes; csr window staged in LDS; octet (8 lanes) = 1 node;
// lane j = feats 8j..8j+7 (uint4 row); 4-deep unroll -> 32 loads in flight/wave.
// BN partials: block-reduce in LDS, then 128 atomicAdds into slot blockIdx&15.
template <int RELU>
__global__ __launch_bounds__(512) void k_agg(
        const __half* __restrict__ y, const int* __restrict__ rowptr,
        const int* __restrict__ csr, const float* __restrict__ dinv,
        const float* __restrict__ bias, __half* __restrict__ hout,
        float* __restrict__ gstats, int N) {
    __shared__ int lcsr[2048];
    __shared__ int lrp[65];
    __shared__ float SW[16][64];            // [0..7]=sum per wave, [8..15]=sumsq
    int t = threadIdx.x;
    int lane = t & 63, wid = t >> 6;        // 8 waves
    int o = lane >> 3, j = lane & 7;        // octet 0..7, lane-in-octet 0..7
    int nodeBase = blockIdx.x * 64;
    if (t < 65) lrp[t] = rowptr[nodeBase + t];
    __syncthreads();
    int wbase = lrp[0];
    int wlen = lrp[64] - wbase;
    bool fits = (wlen <= 2048);
    if (fits)
        for (int i = t; i < wlen; i += 512) lcsr[i] = csr[wbase + i];
    __syncthreads();

    int n = nodeBase + wid * 8 + o;
    int beg = lrp[wid * 8 + o] - wbase;
    int d = lrp[wid * 8 + o + 1] - wbase - beg;
    const uint4* y4 = (const uint4*)y;      // row = 8 uint4 = 128B
    float a[8] = {0, 0, 0, 0, 0, 0, 0, 0};

    if (fits) {
        const int* cp = lcsr + beg;
        int k = 0;
        for (; k + 4 <= d; k += 4) {
            int s0 = cp[k], s1 = cp[k + 1], s2 = cp[k + 2], s3 = cp[k + 3];
            uint4 u0 = y4[(size_t)s0 * 8 + j];
            uint4 u1 = y4[(size_t)s1 * 8 + j];
            uint4 u2 = y4[(size_t)s2 * 8 + j];
            uint4 u3 = y4[(size_t)s3 * 8 + j];
            acc8(a, u0); acc8(a, u1); acc8(a, u2); acc8(a, u3);
        }
        for (; k < d; ++k) {
            uint4 u0 = y4[(size_t)cp[k] * 8 + j];
            acc8(a, u0);
        }
    } else {                                 // ~never (window 32 sigma below cap)
        const int* cp = csr + wbase + beg;
        int k = 0;
        for (; k + 4 <= d; k += 4) {
            int s0 = cp[k], s1 = cp[k + 1], s2 = cp[k + 2], s3 = cp[k + 3];
            uint4 u0 = y4[(size_t)s0 * 8 + j];
            uint4 u1 = y4[(size_t)s1 * 8 + j];
            uint4 u2 = y4[(size_t)s2 * 8 + j];
            uint4 u3 = y4[(size_t)s3 * 8 + j];
            acc8(a, u0); acc8(a, u1); acc8(a, u2); acc8(a, u3);
        }
        for (; k < d; ++k) {
            uint4 u0 = y4[(size_t)cp[k] * 8 + j];
            acc8(a, u0);
        }
    }
    uint4 us = y4[(size_t)n * 8 + j];       // self term
    acc8(a, us);

    float dv = dinv[n];
    const float4* b4 = (const float4*)bias;
    float4 blo = b4[j * 2], bhi = b4[j * 2 + 1];
    float v[8];
    v[0] = a[0] * dv + blo.x; v[1] = a[1] * dv + blo.y;
    v[2] = a[2] * dv + blo.z; v[3] = a[3] * dv + blo.w;
    v[4] = a[4] * dv + bhi.x; v[5] = a[5] * dv + bhi.y;
    v[6] = a[6] * dv + bhi.z; v[7] = a[7] * dv + bhi.w;
    if (RELU) {
#pragma unroll
        for (int i = 0; i < 8; ++i) v[i] = fmaxf(v[i], 0.0f);
    }
    uint4 ov;
    ov.x = pack2h(v[0], v[1]); ov.y = pack2h(v[2], v[3]);
    ov.z = pack2h(v[4], v[5]); ov.w = pack2h(v[6], v[7]);
    ((uint4*)hout)[(size_t)n * 8 + j] = ov;

    // BN partials: combine octets (nodes) then one atomic per feature per block
    float q[8];
#pragma unroll
    for (int i = 0; i < 8; ++i) q[i] = v[i] * v[i];
#pragma unroll
    for (int st = 8; st <= 32; st <<= 1) {
#pragma unroll
        for (int i = 0; i < 8; ++i) {
            v[i] += __shfl_xor(v[i], st);
            q[i] += __shfl_xor(q[i], st);
        }
    }
    if (o == 0) {
#pragma unroll
        for (int i = 0; i < 8; ++i) {
            SW[wid][j * 8 + i] = v[i];
            SW[8 + wid][j * 8 + i] = q[i];
        }
    }
    __syncthreads();
    if (t < 64) {
        float s = 0.0f, qq = 0.0f;
#pragma unroll
        for (int w = 0; w < 8; ++w) {
            s += SW[w][t];
            qq += SW[8 + w][t];
        }
        float* gs = gstats + (blockIdx.x & (NSLOT - 1)) * GSL;  // replicated slot
        atomicAdd(&gs[t * 16], s);
        atomicAdd(&gs[(64 + t) * 16], qq);
    }
}

// fused mean-pool + head: one block per graph (batch sorted -> binary search
// range). 8 waves accumulate BN-normalized features; 16 lanes compute the
// graph's logits + softmax. No atomics, no psum/pcnt.
__global__ __launch_bounds__(512) void k_poolhead(
        const __half* __restrict__ h, const int* __restrict__ batch,
        const float* __restrict__ gstats, float invN,
        const float* __restrict__ clfW, const float* __restrict__ clfb,
        float* __restrict__ out, int N) {
    __shared__ float SWm[8][64];
    __shared__ float pooled[64];
    __shared__ int rng[2];
    int g = blockIdx.x;                 // 64 graphs
    int t = threadIdx.x;                // 512
    int lane = t & 63, wid = t >> 6;
    if (t < 2) {                        // lower_bound(batch, g + t)
        int key = g + t, lo = 0, hi = N;
        while (lo < hi) {
            int mid = (lo + hi) >> 1;
            if (batch[mid] < key) lo = mid + 1; else hi = mid;
        }
        rng[t] = lo;
    }
    // BN constants of final layer (lane = feature)
    float S = 0.0f, Q = 0.0f;
#pragma unroll
    for (int c = 0; c < NSLOT; ++c) {
        S += gstats[c * GSL + lane * 16];
        Q += gstats[c * GSL + (64 + lane) * 16];
    }
    float m = S * invN;
    float r = rsqrtf(Q * invN - m * m + 1e-5f);
    __syncthreads();
    int lo = rng[0], hi = rng[1];
    float acc = 0.0f;
    for (int n = lo + wid; n < hi; n += 8)
        acc += (__half2float(h[(size_t)n * 64 + lane]) - m) * r;
    SWm[wid][lane] = acc;
    __syncthreads();
    if (t < 64) {
        float s = 0.0f;
#pragma unroll
        for (int w = 0; w < 8; ++w) s += SWm[w][t];
        pooled[t] = s / fmaxf((float)(hi - lo), 1.0f);
    }
    __syncthreads();
    if (t < 16) {
        float a = 0.0f;
#pragma unroll 8
        for (int f = 0; f < 64; ++f) a += pooled[f] * clfW[t * 64 + f];
        a += clfb[t];
        float mx = a;
#pragma unroll
        for (int o = 1; o < 16; o <<= 1) mx = fmaxf(mx, __shfl_xor(mx, o, 16));
        float e = __expf(a - mx);
        float sum = e;
#pragma unroll
        for (int o = 1; o < 16; o <<= 1) sum += __shfl_xor(sum, o, 16);
        out[g * 16 + t] = e / sum;
    }
}

extern "C" void kernel_launch(void* const* d_in, const int* in_sizes, int n_in,
                              void* d_out, int out_size, void* d_ws, size_t ws_size,
                              hipStream_t stream) {
    const float* x    = (const float*)d_in[0];
    const int*   ei   = (const int*)d_in[1];
    const int*   bat  = (const int*)d_in[2];
    const float* W0   = (const float*)d_in[3];
    const float* b0   = (const float*)d_in[4];
    const float* W1   = (const float*)d_in[5];
    const float* b1   = (const float*)d_in[6];
    const float* W2   = (const float*)d_in[7];
    const float* b2   = (const float*)d_in[8];
    const float* clfW = (const float*)d_in[9];
    const float* clfb = (const float*)d_in[10];
    float* out = (float*)d_out;

    const int N = in_sizes[0] / 64;   // 65536
    const int E = in_sizes[1] / 2;    // 1048576
    const int AB = N / 64;            // 1024 agg blocks

    char* w = (char*)d_ws;
    size_t off = 0;
    auto take = [&](size_t bytes) -> void* {
        off = (off + 255) & ~(size_t)255;
        void* p = w + off;
        off += bytes;
        return p;
    };
    int*    rowptr   = (int*)take((size_t)(N + 1) * 4);
    int*    bcur     = (int*)take((size_t)NBKT * BSTRIDE * 4);
    float*  dinv     = (float*)take((size_t)N * 4);
    int*    csr      = (int*)take((size_t)E * 4);
    __half* y        = (__half*)take((size_t)N * 64 * 2);
    __half* hA       = (__half*)take((size_t)N * 64 * 2);
    __half* hB       = (__half*)take((size_t)N * 64 * 2);
    float*  gstats   = (float*)take((size_t)3 * NSLOT * GSL * 4);
    // buck (NBKT*CAP ints = 8MB) overlaid on hB (8MB fp16): buck dead after k_place,
    // hB first written in layer-1 k_agg.
    int* buck = (int*)hB;
    float* gs0 = gstats;
    float* gs1 = gstats + NSLOT * GSL;
    float* gs2 = gstats + 2 * NSLOT * GSL;

    const float invN = 1.0f / (float)N;

    k_binit<<<128, 256, 0, stream>>>(bcur, gstats);
    k_bin<<<E / 4096, 256, 0, stream>>>(ei, E, bcur, buck);
    k_place<<<NBKT, 512, 0, stream>>>(bcur, buck, rowptr, dinv, csr, N, E);

    // layer 0 (input x fp32, no BN on input)
    k_gemm<0, 0><<<N / 64, 256, 0, stream>>>(x, W0, nullptr, invN, dinv, y);
    k_agg<1><<<AB, 512, 0, stream>>>(y, rowptr, csr, dinv, b0, hA, gs0, N);
    // layer 1 (BN of layer0 derived from gs0 inside gemm)
    k_gemm<1, 1><<<N / 64, 256, 0, stream>>>(hA, W1, gs0, invN, dinv, y);
    k_agg<1><<<AB, 512, 0, stream>>>(y, rowptr, csr, dinv, b1, hB, gs1, N);
    // layer 2 (no relu)
    k_gemm<1, 1><<<N / 64, 256, 0, stream>>>(hB, W2, gs1, invN, dinv, y);
    k_agg<0><<<AB, 512, 0, stream>>>(y, rowptr, csr, dinv, b2, hA, gs2, N);

    // fused pool (BN of layer2 from gs2) + head: one block per graph (64 graphs)
    k_poolhead<<<64, 512, 0, stream>>>(hA, bat, gs2, invN, clfW, clfb, out, N);
}

// Round 15
// 165.480 us; speedup vs baseline: 1.2052x; 1.2052x over previous
//
#include <hip/hip_runtime.h>
#include <hip/hip_fp16.h>

// GCN: 3x (GEMM(+BN fold from gstats) -> CSR aggregate(+slot-replicated atomic
// BN partials)), then fused pool+head (one block per graph).
// Sizes fixed: N=65536 nodes, E=1048576 edges, F=H=64, 64 graphs, 16 classes.
//
// r8 (188us): 4096-edge bin, scalar-LDS gemm, LDS-staged agg windows.
// r12 (192us): 16-slot replicated gstats stats-fold. r13/14: scanB->place fold
// + pool/head fusion; r14 post-mortem: fused poolhead was LATENCY-SERIAL
// (lane=feature, 1 load in flight/wave, 49us @ 97GB/s). r15: octet-per-node
// uint4 gather (64 nodes in flight/block, 4-deep unroll) + BN-after-reduce
// (mean-pool is linear). 10 dispatches.

#define NBKT 512      // bucket = dst >> 7 (128 nodes per bucket)
#define CAP  4096     // slots per bucket (avg fill 2048)
#define BSTRIDE 16    // padded: one counter per 64B line
#define NSLOT 16      // gstats replication factor
#define GSL   2048    // floats per gstats slot (128 features x 16-stride)

__device__ inline unsigned pack2h(float a, float b) {
    __half ha = __float2half_rn(a), hb = __float2half_rn(b);
    unsigned short ua = *(unsigned short*)&ha, ub = *(unsigned short*)&hb;
    return (unsigned)ua | ((unsigned)ub << 16);
}

__device__ inline void acc8(float* a, uint4 u) {
    __half2* hp = (__half2*)&u;
#pragma unroll
    for (int i = 0; i < 4; ++i) {
        float2 f = __half22float2(hp[i]);
        a[2 * i] += f.x;
        a[2 * i + 1] += f.y;
    }
}

// init bcur + zero gstats (3 layers x 16 slots). 128 blocks.
__global__ void k_binit(int* __restrict__ bcur, float* __restrict__ gstats) {
    int idx = blockIdx.x * 256 + threadIdx.x;   // 0..32767
    if (idx < NBKT) bcur[idx * BSTRIDE] = idx * CAP;
    for (int i = idx; i < 3 * NSLOT * GSL; i += 32768) gstats[i] = 0.0f;
}

// partition edges into NBKT dst-buckets; entries packed (src<<7)|(dst&127)
// 4096 edges/block (r8-proven: 256 blocks, 28KB LDS)
__global__ void k_bin(const int* __restrict__ ei, int E, int* __restrict__ bcur,
                      int* __restrict__ buck) {
    __shared__ int sd[4096];
    __shared__ unsigned short bk[4096];
    __shared__ int cnt[NBKT], off[NBKT];
    int t = threadIdx.x;
    int base = blockIdx.x * 4096;
    for (int i = t; i < NBKT; i += 256) cnt[i] = 0;
    __syncthreads();
#pragma unroll
    for (int k = 0; k < 16; ++k) {
        int i = k * 256 + t;
        int e = base + i;
        int s = ei[e], d = ei[E + e];
        sd[i] = (s << 7) | (d & 127);
        int b = d >> 7;
        bk[i] = (unsigned short)b;
        atomicAdd(&cnt[b], 1);
    }
    __syncthreads();
    for (int b = t; b < NBKT; b += 256) {
        int c = cnt[b];
        off[b] = c ? atomicAdd(&bcur[b * BSTRIDE], c) : 0;
    }
    __syncthreads();
#pragma unroll
    for (int k = 0; k < 16; ++k) {
        int i = k * 256 + t;
        int b = bk[i];
        int p = atomicAdd(&off[b], 1);
        buck[p] = sd[i];
    }
}

// per bucket: redundant in-block scan of all 512 bucket counts -> base;
// count node degrees in LDS, local 128-scan -> rowptr/dinv, scatter csr.
__global__ __launch_bounds__(512) void k_place(
        const int* __restrict__ bcur, const int* __restrict__ buck,
        int* __restrict__ rowptr, float* __restrict__ dinv, int* __restrict__ csr,
        int N, int E) {
    __shared__ int s[NBKT];
    __shared__ int dc[128], sc[128], cur[128];
    __shared__ int sbase;
    int b = blockIdx.x, t = threadIdx.x;   // 512 threads
    // bucket counts -> inclusive scan (Hillis-Steele over 512)
    s[t] = bcur[t * BSTRIDE] - t * CAP;
    if (t < 128) dc[t] = 0;
    __syncthreads();
    for (int o = 1; o < NBKT; o <<= 1) {
        int x = (t >= o) ? s[t - o] : 0;
        __syncthreads();
        s[t] += x;
        __syncthreads();
    }
    if (t == 0) {
        sbase = (b == 0) ? 0 : s[b - 1];   // exclusive prefix at this bucket
        if (b == NBKT - 1) rowptr[N] = E;
    }
    __syncthreads();
    int beg = b * CAP, end = bcur[b * BSTRIDE];
    for (int i = beg + t; i < end; i += 512) atomicAdd(&dc[buck[i] & 127], 1);
    __syncthreads();
    int v = (t < 128) ? dc[t] : 0;
    if (t < 128) sc[t] = v;
    __syncthreads();
    for (int o = 1; o < 128; o <<= 1) {
        int x = 0;
        if (t < 128 && t >= o) x = sc[t - o];
        __syncthreads();
        if (t < 128) sc[t] += x;
        __syncthreads();
    }
    if (t < 128) {
        int r = sbase + sc[t] - v;   // exclusive
        rowptr[b * 128 + t] = r;
        cur[t] = r;
        dinv[b * 128 + t] = rsqrtf((float)(v + 1));  // +1 self loop
    }
    __syncthreads();
    for (int i = beg + t; i < end; i += 512) {
        int e = buck[i];
        int p = atomicAdd(&cur[e & 127], 1);
        csr[p] = e >> 7;
    }
}

// y[n][j] = fp16( dinv[n] * ( sum_f hnorm[n][f]*W[f][j] + brow[j] ) )
// HS: derive mean/rstd of the PREVIOUS layer from 16-slot gstats; fold into Ws.
// r8-proven body: block 256 threads, 64 rows/block; thread = 4x4 tile.
template <int HIN, int HS>
__global__ void k_gemm(const void* __restrict__ hv, const float* __restrict__ W,
                       const float* __restrict__ gstats, float invN,
                       const float* __restrict__ dinv, __half* __restrict__ y) {
    __shared__ float Ws[4096];        // [f][c] 64x64, scaled by rstd[f]
    __shared__ float hs[64 * 65];     // [row][f], stride 65
    __shared__ float sm[64], sr[64], bs[64];
    int t = threadIdx.x;
    int rowBase = blockIdx.x * 64;
    if (t < 64) {
        if (HS) {
            float S = 0.0f, Q = 0.0f;
#pragma unroll
            for (int c = 0; c < NSLOT; ++c) {
                S += gstats[c * GSL + t * 16];
                Q += gstats[c * GSL + (64 + t) * 16];
            }
            float m = S * invN;
            float var = Q * invN - m * m;
            sm[t] = m;
            sr[t] = rsqrtf(var + 1e-5f);
        } else {
            sm[t] = 0.0f;
            sr[t] = 1.0f;
        }
    }
    __syncthreads();
#pragma unroll
    for (int k = 0; k < 4; ++k) {
        int i = t + k * 256;              // float4 index; row f = i>>4
        float4 wv = ((const float4*)W)[i];
        float s = sr[i >> 4];
        wv.x *= s; wv.y *= s; wv.z *= s; wv.w *= s;
        ((float4*)Ws)[i] = wv;
    }
    if (HIN) {
        const uint4* src = (const uint4*)((const __half*)hv + (size_t)rowBase * 64);
#pragma unroll
        for (int k = 0; k < 2; ++k) {
            int i = t + k * 256;          // 0..511 uint4s; each = 8 halves
            int row = i >> 3, c8 = i & 7;
            uint4 u = src[i];
            const __half2* hp = (const __half2*)&u;
            float* dst = &hs[row * 65 + c8 * 8];
#pragma unroll
            for (int j = 0; j < 4; ++j) {
                dst[2 * j + 0] = __low2float(hp[j]);
                dst[2 * j + 1] = __high2float(hp[j]);
            }
        }
    } else {
        const float4* src = (const float4*)((const float*)hv + (size_t)rowBase * 64);
#pragma unroll
        for (int k = 0; k < 4; ++k) {
            int i = t + k * 256;
            int row = i >> 4, c4 = i & 15;
            float4 v = src[i];
            float* dst = &hs[row * 65 + c4 * 4];
            dst[0] = v.x; dst[1] = v.y; dst[2] = v.z; dst[3] = v.w;
        }
    }
    __syncthreads();
    if (t < 64) {
        float acc = 0.0f;
        for (int f = 0; f < 64; ++f) acc += sm[f] * Ws[f * 64 + t];
        bs[t] = -acc;
    }
    __syncthreads();
    int rg = t >> 4;   // 0..15
    int cg = t & 15;   // 0..15
    float4 a0, a1, a2, a3;
    {
        float bx = bs[cg * 4 + 0], by = bs[cg * 4 + 1];
        float bz = bs[cg * 4 + 2], bw = bs[cg * 4 + 3];
        a0 = {bx, by, bz, bw}; a1 = a0; a2 = a0; a3 = a0;
    }
    const float* h0 = &hs[(rg * 4 + 0) * 65];
    const float* h1 = &hs[(rg * 4 + 1) * 65];
    const float* h2 = &hs[(rg * 4 + 2) * 65];
    const float* h3 = &hs[(rg * 4 + 3) * 65];
#pragma unroll 4
    for (int f = 0; f < 64; ++f) {
        float4 wv = ((float4*)Ws)[f * 16 + cg];
        float v0 = h0[f], v1 = h1[f], v2 = h2[f], v3 = h3[f];
        a0.x += v0 * wv.x; a0.y += v0 * wv.y; a0.z += v0 * wv.z; a0.w += v0 * wv.w;
        a1.x += v1 * wv.x; a1.y += v1 * wv.y; a1.z += v1 * wv.z; a1.w += v1 * wv.w;
        a2.x += v2 * wv.x; a2.y += v2 * wv.y; a2.z += v2 * wv.z; a2.w += v2 * wv.w;
        a3.x += v3 * wv.x; a3.y += v3 * wv.y; a3.z += v3 * wv.z; a3.w += v3 * wv.w;
    }
    float d0 = dinv[rowBase + rg * 4 + 0];
    float d1 = dinv[rowBase + rg * 4 + 1];
    float d2 = dinv[rowBase + rg * 4 + 2];
    float d3 = dinv[rowBase + rg * 4 + 3];
    uint2* y2 = (uint2*)y;
    size_t ob = (size_t)(rowBase + rg * 4) * 16 + cg;
    y2[ob + 0]  = {pack2h(a0.x * d0, a0.y * d0), pack2h(a0.z * d0, a0.w * d0)};
    y2[ob + 16] = {pack2h(a1.x * d1, a1.y * d1), pack2h(a1.z * d1, a1.w * d1)};
    y2[ob + 32] = {pack2h(a2.x * d2, a2.y * d2), pack2h(a2.z * d2, a2.w * d2)};
    y2[ob + 48] = {pack2h(a3.x * d3, a3.y * d3), pack2h(a3.z * d3, a3.w * d3)};
}

// out[n] = relu?( dinv[n]*(y[n] + sum_{src} y[src]) + bias ), stored fp16.
// Block = 64 consecutive nodes; csr window staged in LDS; octet (8 lanes) = 1 node;
// lane j = feats 8j..8j+7 (uint4 row); 4-deep unroll -> 32 loads in flight/wave.
// BN partials: block-reduce in LDS, then 128 atomicAdds into slot blockIdx&15.
template <int RELU>
__global__ __launch_bounds__(512) void k_agg(
        const __half* __restrict__ y, const int* __restrict__ rowptr,
        const int* __restrict__ csr, const float* __restrict__ dinv,
        const float* __restrict__ bias, __half* __restrict__ hout,
        float* __restrict__ gstats, int N) {
    __shared__ int lcsr[2048];
    __shared__ int lrp[65];
    __shared__ float SW[16][64];            // [0..7]=sum per wave, [8..15]=sumsq
    int t = threadIdx.x;
    int lane = t & 63, wid = t >> 6;        // 8 waves
    int o = lane >> 3, j = lane & 7;        // octet 0..7, lane-in-octet 0..7
    int nodeBase = blockIdx.x * 64;
    if (t < 65) lrp[t] = rowptr[nodeBase + t];
    __syncthreads();
    int wbase = lrp[0];
    int wlen = lrp[64] - wbase;
    bool fits = (wlen <= 2048);
    if (fits)
        for (int i = t; i < wlen; i += 512) lcsr[i] = csr[wbase + i];
    __syncthreads();

    int n = nodeBase + wid * 8 + o;
    int beg = lrp[wid * 8 + o] - wbase;
    int d = lrp[wid * 8 + o + 1] - wbase - beg;
    const uint4* y4 = (const uint4*)y;      // row = 8 uint4 = 128B
    float a[8] = {0, 0, 0, 0, 0, 0, 0, 0};

    if (fits) {
        const int* cp = lcsr + beg;
        int k = 0;
        for (; k + 4 <= d; k += 4) {
            int s0 = cp[k], s1 = cp[k + 1], s2 = cp[k + 2], s3 = cp[k + 3];
            uint4 u0 = y4[(size_t)s0 * 8 + j];
            uint4 u1 = y4[(size_t)s1 * 8 + j];
            uint4 u2 = y4[(size_t)s2 * 8 + j];
            uint4 u3 = y4[(size_t)s3 * 8 + j];
            acc8(a, u0); acc8(a, u1); acc8(a, u2); acc8(a, u3);
        }
        for (; k < d; ++k) {
            uint4 u0 = y4[(size_t)cp[k] * 8 + j];
            acc8(a, u0);
        }
    } else {                                 // ~never (window 32 sigma below cap)
        const int* cp = csr + wbase + beg;
        int k = 0;
        for (; k + 4 <= d; k += 4) {
            int s0 = cp[k], s1 = cp[k + 1], s2 = cp[k + 2], s3 = cp[k + 3];
            uint4 u0 = y4[(size_t)s0 * 8 + j];
            uint4 u1 = y4[(size_t)s1 * 8 + j];
            uint4 u2 = y4[(size_t)s2 * 8 + j];
            uint4 u3 = y4[(size_t)s3 * 8 + j];
            acc8(a, u0); acc8(a, u1); acc8(a, u2); acc8(a, u3);
        }
        for (; k < d; ++k) {
            uint4 u0 = y4[(size_t)cp[k] * 8 + j];
            acc8(a, u0);
        }
    }
    uint4 us = y4[(size_t)n * 8 + j];       // self term
    acc8(a, us);

    float dv = dinv[n];
    const float4* b4 = (const float4*)bias;
    float4 blo = b4[j * 2], bhi = b4[j * 2 + 1];
    float v[8];
    v[0] = a[0] * dv + blo.x; v[1] = a[1] * dv + blo.y;
    v[2] = a[2] * dv + blo.z; v[3] = a[3] * dv + blo.w;
    v[4] = a[4] * dv + bhi.x; v[5] = a[5] * dv + bhi.y;
    v[6] = a[6] * dv + bhi.z; v[7] = a[7] * dv + bhi.w;
    if (RELU) {
#pragma unroll
        for (int i = 0; i < 8; ++i) v[i] = fmaxf(v[i], 0.0f);
    }
    uint4 ov;
    ov.x = pack2h(v[0], v[1]); ov.y = pack2h(v[2], v[3]);
    ov.z = pack2h(v[4], v[5]); ov.w = pack2h(v[6], v[7]);
    ((uint4*)hout)[(size_t)n * 8 + j] = ov;

    // BN partials: combine octets (nodes) then one atomic per feature per block
    float q[8];
#pragma unroll
    for (int i = 0; i < 8; ++i) q[i] = v[i] * v[i];
#pragma unroll
    for (int st = 8; st <= 32; st <<= 1) {
#pragma unroll
        for (int i = 0; i < 8; ++i) {
            v[i] += __shfl_xor(v[i], st);
            q[i] += __shfl_xor(q[i], st);
        }
    }
    if (o == 0) {
#pragma unroll
        for (int i = 0; i < 8; ++i) {
            SW[wid][j * 8 + i] = v[i];
            SW[8 + wid][j * 8 + i] = q[i];
        }
    }
    __syncthreads();
    if (t < 64) {
        float s = 0.0f, qq = 0.0f;
#pragma unroll
        for (int w = 0; w < 8; ++w) {
            s += SW[w][t];
            qq += SW[8 + w][t];
        }
        float* gs = gstats + (blockIdx.x & (NSLOT - 1)) * GSL;  // replicated slot
        atomicAdd(&gs[t * 16], s);
        atomicAdd(&gs[(64 + t) * 16], qq);
    }
}

// fused mean-pool + head: one block per graph (batch sorted -> binary search).
// Octet-per-node raw-sum gather (lane j = uint4 j of row; 64 nodes in flight
// per block, 4-deep unroll); BN applied AFTER reduction (mean-pool is linear):
// pooled_bn[f] = (rawsum[f]/cnt - m[f]) * r[f]. 16 lanes do logits+softmax.
__global__ __launch_bounds__(512) void k_poolhead(
        const __half* __restrict__ h, const int* __restrict__ batch,
        const float* __restrict__ gstats, float invN,
        const float* __restrict__ clfW, const float* __restrict__ clfb,
        float* __restrict__ out, int N) {
    __shared__ float SWm[8][64];
    __shared__ float pooled[64];
    __shared__ int rng[2];
    int g = blockIdx.x;                 // 64 graphs
    int t = threadIdx.x;                // 512
    int lane = t & 63, wid = t >> 6;
    int o = lane >> 3, j = lane & 7;    // octet = node slot, lane-in-octet = uint4
    if (t < 2) {                        // lower_bound(batch, g + t)
        int key = g + t, lo = 0, hi = N;
        while (lo < hi) {
            int mid = (lo + hi) >> 1;
            if (batch[mid] < key) lo = mid + 1; else hi = mid;
        }
        rng[t] = lo;
    }
    __syncthreads();
    int lo = rng[0], hi = rng[1];
    const uint4* h4 = (const uint4*)h;  // row = 8 uint4 = 128B
    float a[8] = {0, 0, 0, 0, 0, 0, 0, 0};
    int slot = wid * 8 + o;             // 0..63
    for (int n = lo + slot; n < hi; n += 256) {   // 4-deep unroll, clamped tail
        int n1 = n + 64, n2 = n + 128, n3 = n + 192;
        uint4 u0 = h4[(size_t)n * 8 + j];
        uint4 u1 = h4[(size_t)min(n1, hi - 1) * 8 + j];
        uint4 u2 = h4[(size_t)min(n2, hi - 1) * 8 + j];
        uint4 u3 = h4[(size_t)min(n3, hi - 1) * 8 + j];
        acc8(a, u0);
        if (n1 < hi) acc8(a, u1);
        if (n2 < hi) acc8(a, u2);
        if (n3 < hi) acc8(a, u3);
    }
    // combine octets (nodes) within wave: lanes with equal j hold same features
#pragma unroll
    for (int st = 8; st <= 32; st <<= 1) {
#pragma unroll
        for (int i = 0; i < 8; ++i) a[i] += __shfl_xor(a[i], st);
    }
    if (o == 0) {
#pragma unroll
        for (int i = 0; i < 8; ++i) SWm[wid][j * 8 + i] = a[i];
    }
    __syncthreads();
    if (t < 64) {
        float s = 0.0f;
#pragma unroll
        for (int w = 0; w < 8; ++w) s += SWm[w][t];
        // BN of final layer from gstats, applied post-mean (linear)
        float S = 0.0f, Q = 0.0f;
#pragma unroll
        for (int c = 0; c < NSLOT; ++c) {
            S += gstats[c * GSL + t * 16];
            Q += gstats[c * GSL + (64 + t) * 16];
        }
        float m = S * invN;
        float r = rsqrtf(Q * invN - m * m + 1e-5f);
        float mean = s / fmaxf((float)(hi - lo), 1.0f);
        pooled[t] = (mean - m) * r;
    }
    __syncthreads();
    if (t < 16) {
        float acc = 0.0f;
#pragma unroll 8
        for (int f = 0; f < 64; ++f) acc += pooled[f] * clfW[t * 64 + f];
        acc += clfb[t];
        float mx = acc;
#pragma unroll
        for (int oo = 1; oo < 16; oo <<= 1) mx = fmaxf(mx, __shfl_xor(mx, oo, 16));
        float e = __expf(acc - mx);
        float sum = e;
#pragma unroll
        for (int oo = 1; oo < 16; oo <<= 1) sum += __shfl_xor(sum, oo, 16);
        out[g * 16 + t] = e / sum;
    }
}

extern "C" void kernel_launch(void* const* d_in, const int* in_sizes, int n_in,
                              void* d_out, int out_size, void* d_ws, size_t ws_size,
                              hipStream_t stream) {
    const float* x    = (const float*)d_in[0];
    const int*   ei   = (const int*)d_in[1];
    const int*   bat  = (const int*)d_in[2];
    const float* W0   = (const float*)d_in[3];
    const float* b0   = (const float*)d_in[4];
    const float* W1   = (const float*)d_in[5];
    const float* b1   = (const float*)d_in[6];
    const float* W2   = (const float*)d_in[7];
    const float* b2   = (const float*)d_in[8];
    const float* clfW = (const float*)d_in[9];
    const float* clfb = (const float*)d_in[10];
    float* out = (float*)d_out;

    const int N = in_sizes[0] / 64;   // 65536
    const int E = in_sizes[1] / 2;    // 1048576
    const int AB = N / 64;            // 1024 agg blocks

    char* w = (char*)d_ws;
    size_t off = 0;
    auto take = [&](size_t bytes) -> void* {
        off = (off + 255) & ~(size_t)255;
        void* p = w + off;
        off += bytes;
        return p;
    };
    int*    rowptr   = (int*)take((size_t)(N + 1) * 4);
    int*    bcur     = (int*)take((size_t)NBKT * BSTRIDE * 4);
    float*  dinv     = (float*)take((size_t)N * 4);
    int*    csr      = (int*)take((size_t)E * 4);
    __half* y        = (__half*)take((size_t)N * 64 * 2);
    __half* hA       = (__half*)take((size_t)N * 64 * 2);
    __half* hB       = (__half*)take((size_t)N * 64 * 2);
    float*  gstats   = (float*)take((size_t)3 * NSLOT * GSL * 4);
    // buck (NBKT*CAP ints = 8MB) overlaid on hB (8MB fp16): buck dead after k_place,
    // hB first written in layer-1 k_agg.
    int* buck = (int*)hB;
    float* gs0 = gstats;
    float* gs1 = gstats + NSLOT * GSL;
    float* gs2 = gstats + 2 * NSLOT * GSL;

    const float invN = 1.0f / (float)N;

    k_binit<<<128, 256, 0, stream>>>(bcur, gstats);
    k_bin<<<E / 4096, 256, 0, stream>>>(ei, E, bcur, buck);
    k_place<<<NBKT, 512, 0, stream>>>(bcur, buck, rowptr, dinv, csr, N, E);

    // layer 0 (input x fp32, no BN on input)
    k_gemm<0, 0><<<N / 64, 256, 0, stream>>>(x, W0, nullptr, invN, dinv, y);
    k_agg<1><<<AB, 512, 0, stream>>>(y, rowptr, csr, dinv, b0, hA, gs0, N);
    // layer 1 (BN of layer0 derived from gs0 inside gemm)
    k_gemm<1, 1><<<N / 64, 256, 0, stream>>>(hA, W1, gs0, invN, dinv, y);
    k_agg<1><<<AB, 512, 0, stream>>>(y, rowptr, csr, dinv, b1, hB, gs1, N);
    // layer 2 (no relu)
    k_gemm<1, 1><<<N / 64, 256, 0, stream>>>(hB, W2, gs1, invN, dinv, y);
    k_agg<0><<<AB, 512, 0, stream>>>(y, rowptr, csr, dinv, b2, hA, gs2, N);

    // fused pool (BN of layer2 from gs2) + head: one block per graph (64 graphs)
    k_poolhead<<<64, 512, 0, stream>>>(hA, bat, gs2, invN, clfW, clfb, out, N);
}